// Round 1
// baseline (348.090 us; speedup 1.0000x reference)
//
#include <hip/hip_runtime.h>
#include <hip/hip_bf16.h>
#include <stdint.h>

#define Nn 8192
#define Dd 256
#define TWO_N 16384
#define INV_TAU 2.0f

typedef unsigned short u16;
typedef __bf16 bf16x8 __attribute__((ext_vector_type(8)));
typedef float f32x4 __attribute__((ext_vector_type(4)));

typedef const __attribute__((address_space(1))) void* gas_ptr;
typedef __attribute__((address_space(3))) void* las_ptr;

__device__ __forceinline__ void async_copy16(const void* g, void* l) {
  __builtin_amdgcn_global_load_lds((gas_ptr)g, (las_ptr)l, 16, 0, 0);
}

__device__ __forceinline__ u16 f2bf(float x) {
  uint32_t u = __float_as_uint(x);
  u = u + 0x7fffu + ((u >> 16) & 1u);
  return (u16)(u >> 16);
}
__device__ __forceinline__ float bf2f(u16 u) {
  return __uint_as_float(((uint32_t)u) << 16);
}

// ---------------- cast fp32 -> bf16 (4 elems/thread) ----------------
__global__ void cast4_kernel(const float* __restrict__ src, u16* __restrict__ dst, int n4) {
  int i = blockIdx.x * 256 + threadIdx.x;
  if (i < n4) {
    float4 v = ((const float4*)src)[i];
    ushort4 o;
    o.x = f2bf(v.x); o.y = f2bf(v.y); o.z = f2bf(v.z); o.w = f2bf(v.w);
    ((ushort4*)dst)[i] = o;
  }
}

// ---------------- MLP layer GEMM: out[m,n] = sum_k A[m,k]*B[n,k] + bias[n] ----
// EPI 0: elu -> bf16 store ; EPI 1: plain -> f32 store
template<int EPI>
__global__ __launch_bounds__(256)
void mfma_gemm_nt(const u16* __restrict__ A, const u16* __restrict__ B,
                  const float* __restrict__ bias, void* __restrict__ outp,
                  int K, int Ncols) {
  __shared__ __bf16 sA[128 * 64];
  __shared__ __bf16 sB[128 * 64];
  const int i0 = blockIdx.x * 128;
  const int j0 = blockIdx.y * 128;
  const int t = threadIdx.x;
  const int lane = t & 63, wave = t >> 6;
  const int wm = (wave >> 1) * 64, wn = (wave & 1) * 64;
  const int fr = lane >> 4, fc = lane & 15;

  f32x4 acc[4][4];
#pragma unroll
  for (int a = 0; a < 4; a++)
#pragma unroll
    for (int b = 0; b < 4; b++) acc[a][b] = (f32x4){0.f, 0.f, 0.f, 0.f};

  const u16* Ag = A + (size_t)i0 * K;
  const u16* Bg = B + (size_t)j0 * K;

  for (int k0 = 0; k0 < K; k0 += 64) {
    __syncthreads();
#pragma unroll
    for (int it = 0; it < 4; ++it) {
      int c = t + 256 * it;
      int row = c >> 3, kc = (c & 7) * 8;
      async_copy16(Ag + (size_t)row * K + k0 + kc, (void*)&sA[c * 8]);
      async_copy16(Bg + (size_t)row * K + k0 + kc, (void*)&sB[c * 8]);
    }
    __syncthreads();
#pragma unroll
    for (int ks = 0; ks < 2; ++ks) {
      bf16x8 af[4], bfr[4];
#pragma unroll
      for (int mi = 0; mi < 4; mi++)
        af[mi] = *(const bf16x8*)&sA[(wm + mi * 16 + fc) * 64 + ks * 32 + fr * 8];
#pragma unroll
      for (int ni = 0; ni < 4; ni++)
        bfr[ni] = *(const bf16x8*)&sB[(wn + ni * 16 + fc) * 64 + ks * 32 + fr * 8];
#pragma unroll
      for (int mi = 0; mi < 4; mi++)
#pragma unroll
        for (int ni = 0; ni < 4; ni++)
          acc[mi][ni] = __builtin_amdgcn_mfma_f32_16x16x32_bf16(af[mi], bfr[ni], acc[mi][ni], 0, 0, 0);
    }
  }

#pragma unroll
  for (int mi = 0; mi < 4; mi++) {
#pragma unroll
    for (int ni = 0; ni < 4; ni++) {
      int col = j0 + wn + ni * 16 + fc;
      float bv = bias[col];
#pragma unroll
      for (int r = 0; r < 4; r++) {
        int row = i0 + wm + mi * 16 + fr * 4 + r;
        float v = acc[mi][ni][r] + bv;
        if (EPI == 0) {
          v = v > 0.f ? v : (__expf(v) - 1.f);
          ((u16*)outp)[(size_t)row * Ncols + col] = f2bf(v);
        } else {
          ((float*)outp)[(size_t)row * Ncols + col] = v;
        }
      }
    }
  }
}

// ---------------- row-normalize -> bf16 M, plus snorm = ||bf16(n)||^2 ----------
__global__ void normalize_rows(const float* __restrict__ H, u16* __restrict__ Mb,
                               float* __restrict__ snorm) {
  int row = blockIdx.x, lane = threadIdx.x;
  float4 v = ((const float4*)(H + (size_t)row * 256))[lane];
  float ss = v.x * v.x + v.y * v.y + v.z * v.z + v.w * v.w;
#pragma unroll
  for (int off = 32; off; off >>= 1) ss += __shfl_xor(ss, off, 64);
  float rn = 1.f / fmaxf(sqrtf(ss), 1e-12f);
  ushort4 o;
  o.x = f2bf(v.x * rn); o.y = f2bf(v.y * rn); o.z = f2bf(v.z * rn); o.w = f2bf(v.w * rn);
  ((ushort4*)(Mb + (size_t)row * 256))[lane] = o;
  float a0 = bf2f(o.x), a1 = bf2f(o.y), a2 = bf2f(o.z), a3 = bf2f(o.w);
  float s2 = a0 * a0 + a1 * a1 + a2 * a2 + a3 * a3;
#pragma unroll
  for (int off = 32; off; off >>= 1) s2 += __shfl_xor(s2, off, 64);
  if (lane == 0) snorm[row] = s2;
}

// ---------------- fused Gram-exp-rowsum --------------------------------------
// block: 128 rows (blockIdx.x) x 2048 cols chunk (blockIdx.y); r[i] += partials
__global__ __launch_bounds__(256)
void gram_rowsum(const u16* __restrict__ Mb, float* __restrict__ rsum) {
  __shared__ __bf16 sA[128 * 64];
  __shared__ __bf16 sB[128 * 64];
  const int t = threadIdx.x;
  const int lane = t & 63, wave = t >> 6;
  const int wm = (wave >> 1) * 64, wn = (wave & 1) * 64;
  const int fr = lane >> 4, fc = lane & 15;
  const int i0 = blockIdx.x * 128;
  const int jbase = blockIdx.y * 2048;
  const u16* Ag = Mb + (size_t)i0 * 256;

  float rowacc[4][4];
#pragma unroll
  for (int a = 0; a < 4; a++)
#pragma unroll
    for (int r = 0; r < 4; r++) rowacc[a][r] = 0.f;

  for (int jt = 0; jt < 16; ++jt) {
    const u16* Bg = Mb + (size_t)(jbase + jt * 128) * 256;
    f32x4 acc[4][4];
#pragma unroll
    for (int a = 0; a < 4; a++)
#pragma unroll
      for (int b = 0; b < 4; b++) acc[a][b] = (f32x4){0.f, 0.f, 0.f, 0.f};

    for (int k0 = 0; k0 < 256; k0 += 64) {
      __syncthreads();
#pragma unroll
      for (int it = 0; it < 4; ++it) {
        int c = t + 256 * it;
        int row = c >> 3, kc = (c & 7) * 8;
        async_copy16(Ag + (size_t)row * 256 + k0 + kc, (void*)&sA[c * 8]);
        async_copy16(Bg + (size_t)row * 256 + k0 + kc, (void*)&sB[c * 8]);
      }
      __syncthreads();
#pragma unroll
      for (int ks = 0; ks < 2; ++ks) {
        bf16x8 af[4], bfr[4];
#pragma unroll
        for (int mi = 0; mi < 4; mi++)
          af[mi] = *(const bf16x8*)&sA[(wm + mi * 16 + fc) * 64 + ks * 32 + fr * 8];
#pragma unroll
        for (int ni = 0; ni < 4; ni++)
          bfr[ni] = *(const bf16x8*)&sB[(wn + ni * 16 + fc) * 64 + ks * 32 + fr * 8];
#pragma unroll
        for (int mi = 0; mi < 4; mi++)
#pragma unroll
          for (int ni = 0; ni < 4; ni++)
            acc[mi][ni] = __builtin_amdgcn_mfma_f32_16x16x32_bf16(af[mi], bfr[ni], acc[mi][ni], 0, 0, 0);
      }
    }

    // epilogue: exp(2*s), reduce over tile columns (16-lane groups), accumulate
#pragma unroll
    for (int mi = 0; mi < 4; mi++) {
      float v0 = 0.f, v1 = 0.f, v2 = 0.f, v3 = 0.f;
#pragma unroll
      for (int ni = 0; ni < 4; ni++) {
        v0 += __expf(acc[mi][ni][0] * INV_TAU);
        v1 += __expf(acc[mi][ni][1] * INV_TAU);
        v2 += __expf(acc[mi][ni][2] * INV_TAU);
        v3 += __expf(acc[mi][ni][3] * INV_TAU);
      }
#pragma unroll
      for (int off = 1; off < 16; off <<= 1) {
        v0 += __shfl_xor(v0, off, 16);
        v1 += __shfl_xor(v1, off, 16);
        v2 += __shfl_xor(v2, off, 16);
        v3 += __shfl_xor(v3, off, 16);
      }
      rowacc[mi][0] += v0; rowacc[mi][1] += v1; rowacc[mi][2] += v2; rowacc[mi][3] += v3;
    }
  }

  if (fc == 0) {
#pragma unroll
    for (int mi = 0; mi < 4; mi++)
#pragma unroll
      for (int r = 0; r < 4; r++)
        atomicAdd(&rsum[i0 + wm + mi * 16 + fr * 4 + r], rowacc[mi][r]);
  }
}

// ---------------- final loss --------------------------------------------------
__global__ void final_loss(const u16* __restrict__ Mb, const float* __restrict__ rsum,
                           const float* __restrict__ snorm, float* __restrict__ out) {
  int i = blockIdx.x, lane = threadIdx.x;
  ushort4 ua = ((const ushort4*)(Mb + (size_t)i * 256))[lane];
  ushort4 ub = ((const ushort4*)(Mb + (size_t)(Nn + i) * 256))[lane];
  float d = bf2f(ua.x) * bf2f(ub.x) + bf2f(ua.y) * bf2f(ub.y) +
            bf2f(ua.z) * bf2f(ub.z) + bf2f(ua.w) * bf2f(ub.w);
#pragma unroll
  for (int off = 32; off; off >>= 1) d += __shfl_xor(d, off, 64);
  if (lane == 0) {
    float den1 = rsum[i] - __expf(snorm[i] * INV_TAU);
    float den2 = rsum[Nn + i] - __expf(snorm[Nn + i] * INV_TAU);
    out[i] = 0.5f * (logf(den1) + logf(den2)) - d * INV_TAU;
  }
}

extern "C" void kernel_launch(void* const* d_in, const int* in_sizes, int n_in,
                              void* d_out, int out_size, void* d_ws, size_t ws_size,
                              hipStream_t stream) {
  const float* z1 = (const float*)d_in[0];
  const float* z2 = (const float*)d_in[1];
  const float* W1 = (const float*)d_in[2];
  const float* b1 = (const float*)d_in[3];
  const float* W2 = (const float*)d_in[4];
  const float* b2 = (const float*)d_in[5];
  float* out = (float*)d_out;

  char* ws = (char*)d_ws;
  u16*   Zb    = (u16*)(ws);                          // 8 MB (reused as Mb)
  u16*   H1b   = (u16*)(ws + (8u << 20));             // 8 MB
  float* Hf    = (float*)(ws + (16u << 20));          // 16 MB
  u16*   W1b   = (u16*)(ws + (32u << 20));            // 128 KB
  u16*   W2b   = (u16*)(ws + (32u << 20) + 131072);   // 128 KB
  float* rsum  = (float*)(ws + (32u << 20) + 262144); // 64 KB
  float* snorm = (float*)(ws + (32u << 20) + 262144 + 65536); // 64 KB
  u16*   Mb    = Zb;  // Zb dead after layer 1

  int n4z = Nn * Dd / 4;
  cast4_kernel<<<(n4z + 255) / 256, 256, 0, stream>>>(z1, Zb, n4z);
  cast4_kernel<<<(n4z + 255) / 256, 256, 0, stream>>>(z2, Zb + (size_t)Nn * Dd, n4z);
  int n4w = 256 * 256 / 4;
  cast4_kernel<<<(n4w + 255) / 256, 256, 0, stream>>>(W1, W1b, n4w);
  cast4_kernel<<<(n4w + 255) / 256, 256, 0, stream>>>(W2, W2b, n4w);

  // layer 1: elu(Z @ W1^T + b1) -> bf16
  mfma_gemm_nt<0><<<dim3(TWO_N / 128, 2), 256, 0, stream>>>(Zb, W1b, b1, (void*)H1b, 256, 256);
  // layer 2: H1 @ W2^T + b2 -> f32
  mfma_gemm_nt<1><<<dim3(TWO_N / 128, 2), 256, 0, stream>>>(H1b, W2b, b2, (void*)Hf, 256, 256);

  normalize_rows<<<TWO_N, 64, 0, stream>>>(Hf, Mb, snorm);

  hipMemsetAsync(rsum, 0, TWO_N * sizeof(float), stream);
  gram_rowsum<<<dim3(TWO_N / 128, 8), 256, 0, stream>>>(Mb, rsum);

  final_loss<<<Nn, 64, 0, stream>>>(Mb, rsum, snorm, out);
}